// Round 1
// baseline (467.551 us; speedup 1.0000x reference)
//
#include <hip/hip_runtime.h>
#include <hip/hip_bf16.h>
#include <stdint.h>

// Problem constants
#define TOK   25216          // B*N = 128*197
#define CC    768
#define HH    12
#define NKV   224            // 197 padded to 14*16 (and 7*32 for PV k-steps)
#define BHN   1536           // B*H

typedef __attribute__((ext_vector_type(8))) __bf16 bf16x8;   // MFMA A/B frag (4 VGPR)
typedef __attribute__((ext_vector_type(4))) float  f32x4;    // MFMA C/D frag

__device__ __forceinline__ ushort f2bf(float f) {
  union { float f; uint32_t u; } v; v.f = f;
  uint32_t u = v.u;
  u += 0x7FFFu + ((u >> 16) & 1u);          // RTNE
  return (ushort)(u >> 16);
}
__device__ __forceinline__ float bf2f(ushort s) {
  union { uint32_t u; float f; } v; v.u = ((uint32_t)s) << 16; return v.f;
}

__device__ __forceinline__ void gload_lds16(const void* g, void* l) {
  __builtin_amdgcn_global_load_lds(
      (const __attribute__((address_space(1))) unsigned int*)g,
      (__attribute__((address_space(3))) unsigned int*)l, 16, 0, 0);
}

// ---------------- f32 -> bf16 convert (vectorized) ----------------
__global__ __launch_bounds__(256) void conv_bf16(const float* __restrict__ in,
                                                 ushort* __restrict__ out, int n) {
  int idx = (blockIdx.x * 256 + threadIdx.x) * 4;
  if (idx < n) {
    float4 v = *(const float4*)(in + idx);
    ushort4 o;
    o.x = f2bf(v.x); o.y = f2bf(v.y); o.z = f2bf(v.z); o.w = f2bf(v.w);
    *(ushort4*)(out + idx) = o;
  }
}

// ---------------- decay mask: M[h][i][j], padded [12][224][224] bf16 ----------------
__global__ __launch_bounds__(256) void mask_kernel(const float* __restrict__ ai,
                                                   const int* __restrict__ ci,
                                                   ushort* __restrict__ Mb) {
  int h = blockIdx.x / NKV;
  int i = blockIdx.x % NKV;
  int j = threadIdx.x;
  if (j >= NKV) return;
  float val;
  if (j >= 197)      val = 0.f;   // unused (forced -inf logit)
  else if (i >= 197) val = 1.f;   // unused (rows never stored)
  else if (i == 0 || j == 0) val = 1.f;  // cls row/col of ones
  else {
    float acc = 0.f;
#pragma unroll
    for (int c = 0; c < 6; ++c) {
      float a  = ai[c * 12 + h];
      float p  = 1.f / (1.f + expf(-a));
      float l2 = log2f(p);
      int   e  = ci[c * 196 + i - 1] - ci[c * 196 + j - 1];
      if (e < 0) e = -e;
      acc += exp2f(l2 * (float)e);
    }
    val = acc * (1.f / 6.f);
  }
  Mb[((size_t)h * NKV + i) * NKV + j] = f2bf(val);
}

// ---------------- 128x128 tile bf16 GEMM (m97 structure, BK=64, XOR-swizzled LDS) ----
// EPI=0: qkv -> scatter into Q/K [bh][224][64] and Vt [bh][64][224] (bf16)
// EPI=1: proj -> f32 out + bias
template <int EPI, int NT>
__global__ __launch_bounds__(256) void gemm128(
    const ushort* __restrict__ A, const ushort* __restrict__ Bw,
    ushort* __restrict__ Qb, ushort* __restrict__ Kb, ushort* __restrict__ Vtb,
    const float* __restrict__ bias, float* __restrict__ outp) {
  __shared__ alignas(16) char As[128 * 128];
  __shared__ alignas(16) char Bs[128 * 128];
  const int tid = threadIdx.x;
  const int lane = tid & 63, wid = tid >> 6;
  const int g = lane >> 4, li = lane & 15;
  const int m0 = (blockIdx.x / NT) * 128;
  const int n0 = (blockIdx.x % NT) * 128;
  const int wr = wid >> 1, wc = wid & 1;

  f32x4 acc[4][4];
  f32x4 zero = {0.f, 0.f, 0.f, 0.f};
#pragma unroll
  for (int i = 0; i < 4; ++i)
#pragma unroll
    for (int j = 0; j < 4; ++j) acc[i][j] = zero;

  for (int kk = 0; kk < 768; kk += 64) {
    // stage A,B tiles: linear LDS dest, inverse-XOR-swizzled global source (m173)
#pragma unroll
    for (int p = 0; p < 4; ++p) {
      int o = tid * 16 + p * 4096;           // byte offset in 16KB tile
      int row = o >> 7;
      int cs = (o & 127) ^ ((row & 7) << 4);
      gload_lds16(A + (size_t)(m0 + row) * 768 + kk + (cs >> 1), As + o);
      gload_lds16(Bw + (size_t)(n0 + row) * 768 + kk + (cs >> 1), Bs + o);
    }
    __syncthreads();
#pragma unroll
    for (int ks = 0; ks < 2; ++ks) {
      bf16x8 af[4], bfr[4];
#pragma unroll
      for (int mt = 0; mt < 4; ++mt) {
        int row = wr * 64 + mt * 16 + li;
        int c = (ks * 64 + g * 16) ^ ((row & 7) << 4);
        af[mt] = *(const bf16x8*)(As + row * 128 + c);
      }
#pragma unroll
      for (int nt = 0; nt < 4; ++nt) {
        int row = wc * 64 + nt * 16 + li;
        int c = (ks * 64 + g * 16) ^ ((row & 7) << 4);
        bfr[nt] = *(const bf16x8*)(Bs + row * 128 + c);
      }
#pragma unroll
      for (int mt = 0; mt < 4; ++mt)
#pragma unroll
        for (int nt = 0; nt < 4; ++nt)
          acc[mt][nt] = __builtin_amdgcn_mfma_f32_16x16x32_bf16(
              af[mt], bfr[nt], acc[mt][nt], 0, 0, 0);
    }
    __syncthreads();
  }

  if (EPI == 0) {
    const int s3 = n0 / 768;   // 0=q, 1=k, 2=v (block-uniform: 128 | 768)
#pragma unroll
    for (int nt = 0; nt < 4; ++nt) {
      int n = n0 + wc * 64 + nt * 16 + li;
      int rem = n - s3 * 768;
      int hh = rem >> 6, d = rem & 63;
#pragma unroll
      for (int mt = 0; mt < 4; ++mt) {
#pragma unroll
        for (int r = 0; r < 4; ++r) {
          int m = m0 + wr * 64 + mt * 16 + 4 * g + r;
          uint32_t bI = ((uint32_t)m * 85164u) >> 24;  // m/197 (exact for m<25216)
          int tok = m - (int)bI * 197;
          ushort val = f2bf(acc[mt][nt][r]);
          size_t bh = (size_t)bI * 12 + hh;
          if (s3 == 0)      Qb[(bh * NKV + tok) * 64 + d] = val;
          else if (s3 == 1) Kb[(bh * NKV + tok) * 64 + d] = val;
          else              Vtb[(bh * 64 + d) * NKV + tok] = val;
        }
      }
    }
  } else {
#pragma unroll
    for (int nt = 0; nt < 4; ++nt) {
      int n = n0 + wc * 64 + nt * 16 + li;
      float bv = bias[n];
#pragma unroll
      for (int mt = 0; mt < 4; ++mt) {
#pragma unroll
        for (int r = 0; r < 4; ++r) {
          int m = m0 + wr * 64 + mt * 16 + 4 * g + r;
          outp[(size_t)m * 768 + n] = acc[mt][nt][r] + bv;
        }
      }
    }
  }
}

// ---------------- fused masked attention, one block per (b,h) --------------------
// Swapped QK^T: S^T = mfma(K, Q^T) so each lane owns one q-row (i = lane&15);
// softmax reduce = 2x shfl_xor. P staged per-wave in LDS for the PV A-fragment.
#define KL_S 72    // Kl row stride (ushorts): 144B -> 2-way banks max
#define VL_S 232   // Vl/Pl row stride: 464B -> 2-way banks max
__global__ __launch_bounds__(448) void attn_kernel(
    const ushort* __restrict__ Qb, const ushort* __restrict__ Kb,
    const ushort* __restrict__ Vtb, const ushort* __restrict__ Mb,
    ushort* __restrict__ Ob) {
  __shared__ alignas(16) ushort Kl[NKV * KL_S];     // 32256 B
  __shared__ alignas(16) ushort Vl[64 * VL_S];      // 29696 B
  __shared__ alignas(16) ushort Pl[7 * 16 * VL_S];  // 51968 B
  const int tid = threadIdx.x, lane = tid & 63, wid = tid >> 6;
  const int g = lane >> 4, li = lane & 15;
  const int bh = blockIdx.x;
  const int b = bh / 12, h = bh % 12;

  const ushort* Kg = Kb + (size_t)bh * (NKV * 64);
  const ushort* Vg = Vtb + (size_t)bh * (64 * NKV);
  const ushort* Qg = Qb + (size_t)bh * (NKV * 64);

  // stage K [224][64] -> Kl (stride 72), V^T [64][224] -> Vl (stride 232)
#pragma unroll
  for (int p = 0; p < 4; ++p) {
    int o = (tid + p * 448) * 16;               // byte offset, 28672 total
    int row = o >> 7, c = o & 127;
    *(bf16x8*)((char*)Kl + row * 144 + c) = *(const bf16x8*)((const char*)Kg + o);
  }
#pragma unroll
  for (int p = 0; p < 4; ++p) {
    int o = (tid + p * 448) * 16;
    int row = o / 448, c = o % 448;
    *(bf16x8*)((char*)Vl + row * 464 + c) = *(const bf16x8*)((const char*)Vg + o);
  }
  __syncthreads();

  for (int t = 0; t < 2; ++t) {
    int rt = wid * 2 + t;                       // 14 row-tiles over 7 waves
    int r0 = rt * 16;
    if (r0 >= 197) continue;                    // tile 13 fully padded
    // Q fragments straight from global (read once, reused 14x)
    bf16x8 qf[2];
#pragma unroll
    for (int ks = 0; ks < 2; ++ks)
      qf[ks] = *(const bf16x8*)(Qg + (size_t)(r0 + li) * 64 + ks * 32 + g * 8);

    // S^T: acc[ct] holds (j = ct*16+4g+r, i = r0+li)
    f32x4 acc[14];
#pragma unroll
    for (int ct = 0; ct < 14; ++ct) {
      bf16x8 kf0 = *(const bf16x8*)((const char*)Kl + (ct * 16 + li) * 144 + g * 16);
      bf16x8 kf1 = *(const bf16x8*)((const char*)Kl + (ct * 16 + li) * 144 + 64 + g * 16);
      f32x4 z = {0.f, 0.f, 0.f, 0.f};
      z = __builtin_amdgcn_mfma_f32_16x16x32_bf16(kf0, qf[0], z, 0, 0, 0);
      acc[ct] = __builtin_amdgcn_mfma_f32_16x16x32_bf16(kf1, qf[1], z, 0, 0, 0);
    }

    // logits in place: L = (S * 1/8) * M[h][i][j]; -1e30 for j>=197
    int ig = r0 + li;
    const ushort* Mrow = Mb + ((size_t)h * NKV + ig) * NKV;
    float mx = -3e38f;
#pragma unroll
    for (int ct = 0; ct < 14; ++ct) {
      int j0 = ct * 16 + 4 * g;
      ushort4 mv = *(const ushort4*)(Mrow + j0);
#pragma unroll
      for (int r = 0; r < 4; ++r) {
        float Lv = (j0 + r < 197)
                     ? acc[ct][r] * 0.125f * bf2f(((const ushort*)&mv)[r])
                     : -1e30f;
        acc[ct][r] = Lv;
        mx = fmaxf(mx, Lv);
      }
    }
    mx = fmaxf(mx, __shfl_xor(mx, 16));
    mx = fmaxf(mx, __shfl_xor(mx, 32));

    float sum = 0.f;
    ushort* Prow = Pl + ((size_t)wid * 16 + li) * VL_S;
#pragma unroll
    for (int ct = 0; ct < 14; ++ct) {
      ushort4 pv;
#pragma unroll
      for (int r = 0; r < 4; ++r) {
        float p = exp2f((acc[ct][r] - mx) * 1.44269504f);  // 0 for masked j
        sum += p;
        ((ushort*)&pv)[r] = f2bf(p);
      }
      *(ushort4*)(Prow + ct * 16 + 4 * g) = pv;            // 8B store
    }
    sum += __shfl_xor(sum, 16);
    sum += __shfl_xor(sum, 32);

    asm volatile("s_waitcnt lgkmcnt(0)" ::: "memory");     // P visible to own wave
    __builtin_amdgcn_sched_barrier(0);

    // PV: O[i][d] = P @ V, A=P (row=i=li), B=V (col=d=li)
    f32x4 oacc[4];
#pragma unroll
    for (int dt = 0; dt < 4; ++dt) oacc[dt] = (f32x4){0.f, 0.f, 0.f, 0.f};
    const ushort* Pbase = Pl + (size_t)wid * 16 * VL_S;
#pragma unroll
    for (int ks = 0; ks < 7; ++ks) {
      bf16x8 pf = *(const bf16x8*)(Pbase + (size_t)li * VL_S + ks * 32 + g * 8);
#pragma unroll
      for (int dt = 0; dt < 4; ++dt) {
        bf16x8 vf = *(const bf16x8*)(Vl + (size_t)(dt * 16 + li) * VL_S + ks * 32 + g * 8);
        oacc[dt] = __builtin_amdgcn_mfma_f32_16x16x32_bf16(pf, vf, oacc[dt], 0, 0, 0);
      }
    }
    // normalize + store (D rows i_local = 4g+r; rowsum lives in lane (4g+r))
    float inv[4];
#pragma unroll
    for (int r = 0; r < 4; ++r) {
      float sr = __shfl(sum, 4 * g + r);
      inv[r] = 1.f / sr;
    }
#pragma unroll
    for (int dt = 0; dt < 4; ++dt) {
      int d = dt * 16 + li;
#pragma unroll
      for (int r = 0; r < 4; ++r) {
        int tokn = r0 + 4 * g + r;
        if (tokn < 197) {
          size_t rowi = (size_t)b * 197 + tokn;
          Ob[rowi * 768 + h * 64 + d] = f2bf(oacc[dt][r] * inv[r]);
        }
      }
    }
  }
}

// ---------------- host ----------------
extern "C" void kernel_launch(void* const* d_in, const int* in_sizes, int n_in,
                              void* d_out, int out_size, void* d_ws, size_t ws_size,
                              hipStream_t stream) {
  const float* x      = (const float*)d_in[0];
  const float* w_qkv  = (const float*)d_in[1];
  const float* w_proj = (const float*)d_in[2];
  const float* b_proj = (const float*)d_in[3];
  const float* ai     = (const float*)d_in[4];
  const int*   ci     = (const int*)d_in[5];
  float* out = (float*)d_out;

  // ws layout (ushort elements)
  ushort* x_bf    = (ushort*)d_ws;                          // 25216*768
  ushort* wqkv_bf = x_bf + (size_t)TOK * CC;                // 2304*768
  ushort* wproj_bf= wqkv_bf + (size_t)2304 * CC;            // 768*768
  ushort* Qb      = wproj_bf + (size_t)CC * CC;             // 1536*224*64
  ushort* Kb      = Qb + (size_t)BHN * NKV * 64;
  ushort* Vtb     = Kb + (size_t)BHN * NKV * 64;
  ushort* Mb      = Vtb + (size_t)BHN * NKV * 64;           // 12*224*224
  ushort* Ob      = x_bf;  // reuse: x_bf dead after qkv GEMM

  conv_bf16<<<(TOK * CC / 4 + 255) / 256, 256, 0, stream>>>(x, x_bf, TOK * CC);
  conv_bf16<<<(2304 * CC / 4 + 255) / 256, 256, 0, stream>>>(w_qkv, wqkv_bf, 2304 * CC);
  conv_bf16<<<(CC * CC / 4 + 255) / 256, 256, 0, stream>>>(w_proj, wproj_bf, CC * CC);
  mask_kernel<<<12 * NKV, 256, 0, stream>>>(ai, ci, Mb);
  gemm128<0, 18><<<197 * 18, 256, 0, stream>>>(x_bf, wqkv_bf, Qb, Kb, Vtb, nullptr, nullptr);
  attn_kernel<<<BHN, 448, 0, stream>>>(Qb, Kb, Vtb, Mb, Ob);
  gemm128<1, 6><<<197 * 6, 256, 0, stream>>>(Ob, wproj_bf, nullptr, nullptr, nullptr, b_proj, out);
}